// Round 7
// baseline (122.142 us; speedup 1.0000x reference)
//
#include <hip/hip_runtime.h>
#include <hip/hip_bf16.h>
#include <stdint.h>

#define BB 8
#define LL 2048
#define DD 64

typedef short bf16x8 __attribute__((ext_vector_type(8)));  // 8 bf16 (4 VGPRs)
typedef float f32x4 __attribute__((ext_vector_type(4)));
typedef unsigned short ushort_t;
typedef __attribute__((address_space(1))) const unsigned int gas_u32;
typedef __attribute__((address_space(3))) unsigned int las_u32;

// ---- helpers --------------------------------------------------------------
__device__ __forceinline__ unsigned pk2(float lo, float hi) {
    union { __hip_bfloat162 h; unsigned u; } c;
    c.h = __float22bfloat162_rn(make_float2(lo, hi));   // v_cvt_pk_bf16_f32
    return c.u;
}
__device__ __forceinline__ float4 ld4(const float* __restrict__ p) {
    return *reinterpret_cast<const float4*>(p);
}
__device__ __forceinline__ bf16x8 cvt8f(float4 a, float4 b) {
    union { bf16x8 v; unsigned u[4]; } r;
    r.u[0] = pk2(a.x, a.y); r.u[1] = pk2(a.z, a.w);
    r.u[2] = pk2(b.x, b.y); r.u[3] = pk2(b.z, b.w);
    return r.v;
}
// async global->LDS, 16B/lane; LDS dst = wave-uniform base + lane*16 (HW rule)
__device__ __forceinline__ void glds16(const void* g, void* lds_base_uniform) {
    __builtin_amdgcn_global_load_lds((gas_u32*)g, (las_u32*)lds_base_uniform, 16, 0, 0);
}
__device__ __forceinline__ float bfu2f(unsigned bits) {
    union { unsigned u; float f; } c; c.u = bits << 16; return c.f;
}
// fallback-kernel helpers (round-2 proven)
__device__ __forceinline__ unsigned f2bf_u(float f) {
    union { float f; unsigned u; } v; v.f = f;
    return (v.u + 0x8000u) >> 16;
}
__device__ __forceinline__ bf16x8 cvt8(const float* __restrict__ p) {
    float4 a = ld4(p), b = ld4(p + 4);
    union { bf16x8 v; unsigned u[4]; } r;
    r.u[0] = f2bf_u(a.x) | (f2bf_u(a.y) << 16);
    r.u[1] = f2bf_u(a.z) | (f2bf_u(a.w) << 16);
    r.u[2] = f2bf_u(b.x) | (f2bf_u(b.y) << 16);
    r.u[3] = f2bf_u(b.z) | (f2bf_u(b.w) << 16);
    return r.v;
}

// ---- prep 1: K fp32 [b][k][d] -> bf16 same layout -------------------------
__global__ __launch_bounds__(256) void pack_k_bf16(const float* __restrict__ K,
                                                   ushort_t* __restrict__ Kb) {
    size_t i = ((size_t)blockIdx.x * 256 + threadIdx.x) * 8;
    float4 a = ld4(K + i), b = ld4(K + i + 4);
    uint4 o = { pk2(a.x, a.y), pk2(a.z, a.w), pk2(b.x, b.y), pk2(b.z, b.w) };
    *reinterpret_cast<uint4*>(Kb + i) = o;
}

// ---- prep 2: V fp32 [b][k][d] -> bf16 transposed [b][d][k] ----------------
__global__ __launch_bounds__(256) void transpose_v_bf(const float* __restrict__ V,
                                                      ushort_t* __restrict__ VT) {
    __shared__ float t[64][65];
    const int b  = blockIdx.x >> 5;
    const int kt = (blockIdx.x & 31) << 6;
    {
        const int r  = threadIdx.x >> 2;
        const int cq = (threadIdx.x & 3) << 4;
        const float* src = V + ((size_t)(b * LL + kt + r)) * DD + cq;
        #pragma unroll
        for (int i = 0; i < 4; ++i) {
            float4 v = ld4(src + 4 * i);
            t[r][cq + 4 * i + 0] = v.x; t[r][cq + 4 * i + 1] = v.y;
            t[r][cq + 4 * i + 2] = v.z; t[r][cq + 4 * i + 3] = v.w;
        }
    }
    __syncthreads();
    {
        const int d  = threadIdx.x >> 2;
        const int kq = (threadIdx.x & 3) << 4;
        ushort_t* dst = VT + ((size_t)(b * DD + d)) * LL + kt + kq;
        #pragma unroll
        for (int u = 0; u < 2; ++u) {
            uint4 o;
            o.x = pk2(t[kq + 8 * u + 0][d], t[kq + 8 * u + 1][d]);
            o.y = pk2(t[kq + 8 * u + 2][d], t[kq + 8 * u + 3][d]);
            o.z = pk2(t[kq + 8 * u + 4][d], t[kq + 8 * u + 5][d]);
            o.w = pk2(t[kq + 8 * u + 6][d], t[kq + 8 * u + 7][d]);
            *reinterpret_cast<uint4*>(dst + 8 * u) = o;
        }
    }
}

// ---- main attention kernel ------------------------------------------------
// Block = 256 thr = 4 waves; 32 q/block; k swept in 16 tiles of 128.
// Waves = k-quarters (h=0..3, 32k each); each wave computes BOTH 16-q
// subtiles, sharing its K/V LDS fragments (16 MFMA per 8 ds_read_b128).
// Grid = 8b x 64 qtiles = 512 blocks -> 2 blocks/CU (decoupled barriers).
// Staging: global_load_lds width 16, double-buffered, XOR-swizzled.
// Inner math identical to verified R3..R6: S^T = K*Q^T, exp*kmask,
// cross-quad shuffle P-transform, PV with V^T B-frags, LDS-atomic combine.
__global__ __launch_bounds__(256, 2) void attn6(
    const float* __restrict__ Q,
    const ushort_t* __restrict__ Kbf,
    const ushort_t* __restrict__ VTb,
    const int* __restrict__ qmask,
    const int* __restrict__ kmask,
    float* __restrict__ Out)
{
    const int tid  = threadIdx.x;
    const int h    = tid >> 6;         // wave = k-quarter 0..3
    const int lane = tid & 63;
    const int ln   = lane & 15;
    const int quad = lane >> 4;

    const int b  = blockIdx.x >> 6;          // 8 batches
    const int q0 = (blockIdx.x & 63) << 5;   // 32 q per block

    __shared__ char     lds[2][32768];   // per buf: K 16KB ([128k][8 gran]) + V 16KB ([64d][16 gran])
    __shared__ ushort_t kmbf[LL];        // kmask as bf16 (1.0/0.0)
    __shared__ float    Osum[32][68];
    __shared__ float    Dsum[32];

    // staging geometry (per lane, 4 K-granules + 4 V-granules per tile)
    const char* Kg = (const char*)Kbf + (size_t)b * LL * DD * 2;
    const char* Vg = (const char*)VTb + (size_t)b * DD * LL * 2;
    int kr[4], kc[4], vd[4], vc[4];
    #pragma unroll
    for (int i = 0; i < 4; ++i) {
        const int chunk = h * 4 + i;
        kr[i] = 8 * chunk + (lane >> 3);          // K row (k-local)
        kc[i] = (lane & 7) ^ (kr[i] & 7);         // swizzled K src granule
        vd[i] = 4 * chunk + (lane >> 4);          // V row (d)
        vc[i] = (lane & 15) ^ (vd[i] & 15);       // swizzled V src granule
    }

    #define STAGE(buf, k0)                                                     \
        do {                                                                   \
            _Pragma("unroll")                                                  \
            for (int i_ = 0; i_ < 4; ++i_) {                                   \
                glds16(Kg + (size_t)((k0) + kr[i_]) * 128 + kc[i_] * 16,       \
                       &lds[buf][(h * 4 + i_) * 1024]);                        \
                glds16(Vg + (size_t)vd[i_] * (LL * 2) + (k0) * 2 + vc[i_] * 16,\
                       &lds[buf][16384 + (h * 4 + i_) * 1024]);                \
            }                                                                  \
        } while (0)

    STAGE(0, 0);   // issue tile-0 staging ASAP; drained by first barrier

    // prologue (overlaps staging): zero accum, kmask->bf16, Q fragments
    for (int i = tid; i < 32 * 68; i += 256) (&Osum[0][0])[i] = 0.f;
    if (tid < 32) Dsum[tid] = 0.f;
    {
        const int* kp = kmask + b * LL + tid * 8;
        int4 a = *reinterpret_cast<const int4*>(kp);
        int4 c = *reinterpret_cast<const int4*>(kp + 4);
        uint4 u;
        u.x = (a.x ? 0x3F80u : 0u) | ((a.y ? 0x3F80u : 0u) << 16);
        u.y = (a.z ? 0x3F80u : 0u) | ((a.w ? 0x3F80u : 0u) << 16);
        u.z = (c.x ? 0x3F80u : 0u) | ((c.y ? 0x3F80u : 0u) << 16);
        u.w = (c.z ? 0x3F80u : 0u) | ((c.w ? 0x3F80u : 0u) << 16);
        *reinterpret_cast<uint4*>(kmbf + tid * 8) = u;
    }
    bf16x8 qf[2][2];   // [subtile][d-half]; q = q0+16s+ln, d = dh*32+quad*8+j
    #pragma unroll
    for (int s = 0; s < 2; ++s) {
        const float* qp = Q + ((size_t)(b * LL + q0 + 16 * s + ln)) * DD + quad * 8;
        qf[s][0] = cvt8f(ld4(qp),      ld4(qp + 4));
        qf[s][1] = cvt8f(ld4(qp + 32), ld4(qp + 36));
    }

    f32x4 Oacc[2][4];
    #pragma unroll
    for (int s = 0; s < 2; ++s)
        #pragma unroll
        for (int d = 0; d < 4; ++d) Oacc[s][d] = (f32x4){0.f, 0.f, 0.f, 0.f};
    float dsum[2] = {0.f, 0.f};

    const int src0 = ln + ((quad & 1) << 5);
    const int src1 = src0 + 16;
    const bool hi  = quad >= 2;
    const float EC = 0.125f * 1.44269504f;   // exp(s/8) = exp2(s*EC)

    #pragma unroll 2
    for (int it = 0; it < 16; ++it) {
        __syncthreads();   // vmcnt(0) drain: tile `it` staged; other buf free
        if (it != 15) STAGE((it + 1) & 1, (it + 1) * 128);

        const int   k0 = it * 128;
        const char* LK = lds[it & 1];
        const char* LV = lds[it & 1] + 16384;

        // K A-frags (shared by both subtiles): rows 32h+16tt+ln
        bf16x8 kf[2][2];
        #pragma unroll
        for (int tt = 0; tt < 2; ++tt) {
            const int r = 32 * h + 16 * tt + ln;
            #pragma unroll
            for (int dh = 0; dh < 2; ++dh) {
                const int c = (dh * 4 + quad) ^ (ln & 7);
                kf[tt][dh] = *reinterpret_cast<const bf16x8*>(LK + r * 128 + c * 16);
            }
        }
        // V B-frags: d = db*16+ln, k-local = 32h+8quad+j
        bf16x8 vf[4];
        #pragma unroll
        for (int db = 0; db < 4; ++db) {
            const int d = db * 16 + ln;
            const int c = (4 * h + quad) ^ ln;
            vf[db] = *reinterpret_cast<const bf16x8*>(LV + d * 256 + c * 16);
        }
        // kmask floats for this wave's 32k (shared by both subtiles)
        float4 fm[2];
        #pragma unroll
        for (int tt = 0; tt < 2; ++tt) {
            ushort4 mu = *reinterpret_cast<const ushort4*>(
                kmbf + k0 + 32 * h + 16 * tt + 4 * quad);
            fm[tt] = make_float4(bfu2f(mu.x), bfu2f(mu.y), bfu2f(mu.z), bfu2f(mu.w));
        }

        #pragma unroll
        for (int s = 0; s < 2; ++s) {
            // S^T tiles: lane holds P^T[k=16tt+4quad+r (in wave window)][q=ln]
            unsigned w[2][2];
            #pragma unroll
            for (int tt = 0; tt < 2; ++tt) {
                f32x4 acc = (f32x4){0.f, 0.f, 0.f, 0.f};
                acc = __builtin_amdgcn_mfma_f32_16x16x32_bf16(kf[tt][0], qf[s][0], acc, 0, 0, 0);
                acc = __builtin_amdgcn_mfma_f32_16x16x32_bf16(kf[tt][1], qf[s][1], acc, 0, 0, 0);
                float e0 = exp2f(acc[0] * EC) * fm[tt].x;
                float e1 = exp2f(acc[1] * EC) * fm[tt].y;
                float e2 = exp2f(acc[2] * EC) * fm[tt].z;
                float e3 = exp2f(acc[3] * EC) * fm[tt].w;
                dsum[s] += (e0 + e1) + (e2 + e3);
                w[tt][0] = pk2(e0, e1);
                w[tt][1] = pk2(e2, e3);
            }
            // P^T(C-layout) -> P(A-layout): cross-quad permutation (verified)
            union { bf16x8 v; unsigned u[4]; } pf;
            {
                unsigned a0 = __shfl(w[0][0], src0), b0 = __shfl(w[1][0], src0);
                unsigned a1 = __shfl(w[0][1], src0), b1 = __shfl(w[1][1], src0);
                unsigned a2 = __shfl(w[0][0], src1), b2 = __shfl(w[1][0], src1);
                unsigned a3 = __shfl(w[0][1], src1), b3 = __shfl(w[1][1], src1);
                pf.u[0] = hi ? b0 : a0;
                pf.u[1] = hi ? b1 : a1;
                pf.u[2] = hi ? b2 : a2;
                pf.u[3] = hi ? b3 : a3;
            }
            #pragma unroll
            for (int db = 0; db < 4; ++db)
                Oacc[s][db] = __builtin_amdgcn_mfma_f32_16x16x32_bf16(pf.v, vf[db], Oacc[s][db], 0, 0, 0);
        }
    }
    #undef STAGE

    // den: reduce over quads (q = ln within subtile s)
    #pragma unroll
    for (int s = 0; s < 2; ++s) {
        float v = dsum[s];
        v += __shfl_xor(v, 16);
        v += __shfl_xor(v, 32);
        dsum[s] = v;
    }

    // combine the 4 k-quarter waves via LDS atomics (verified epilogue)
    #pragma unroll
    for (int s = 0; s < 2; ++s)
        #pragma unroll
        for (int db = 0; db < 4; ++db)
            #pragma unroll
            for (int r = 0; r < 4; ++r)
                atomicAdd(&Osum[16 * s + quad * 4 + r][db * 16 + ln], Oacc[s][db][r]);
    if (quad == 0) {
        atomicAdd(&Dsum[ln], dsum[0]);
        atomicAdd(&Dsum[16 + ln], dsum[1]);
    }
    __syncthreads();

    // normalize by max(den,1), apply q_mask, store fp32
    const int q  = tid >> 3;           // 0..31
    const int d0 = (tid & 7) << 3;     // 0..56
    float dn  = Dsum[q];
    float inv = 1.0f / fmaxf(dn, 1.0f);
    float sc  = qmask[b * LL + q0 + q] ? inv : 0.0f;
    f32x4 o0 = *reinterpret_cast<const f32x4*>(&Osum[q][d0])     * sc;
    f32x4 o1 = *reinterpret_cast<const f32x4*>(&Osum[q][d0 + 4]) * sc;
    float* op = Out + ((size_t)(b * LL + q0 + q)) * DD + d0;
    *reinterpret_cast<f32x4*>(op)     = o0;
    *reinterpret_cast<f32x4*>(op + 4) = o1;
}

// ---- fallback (round-2 kernel, used only if ws too small) -----------------
__global__ __launch_bounds__(256, 4) void attn_mfma(
    const float* __restrict__ Q, const float* __restrict__ K,
    const float* __restrict__ V, const int* __restrict__ qmask,
    const int* __restrict__ kmask, float* __restrict__ Out)
{
    const int tid  = threadIdx.x;
    const int wave = tid >> 6;
    const int lane = tid & 63;
    const int n    = lane & 15;
    const int quad = lane >> 4;
    const int bx = blockIdx.x;
    const int b  = bx >> 7;
    const int q0 = (bx & 127) << 4;
    __shared__ float Pl[4][576];
    __shared__ float Opart[4][16][68];
    __shared__ float Denp[4][16];
    const float* Qp = Q + ((size_t)(b * LL + q0 + n)) * DD + quad * 8;
    bf16x8 qf0 = cvt8(Qp);
    bf16x8 qf1 = cvt8(Qp + 32);
    const float* Kb = K + ((size_t)(b * LL) + n) * DD + quad * 8;
    const float* Vb = V + ((size_t)(b * LL) + quad * 8) * DD + n;
    const int* kmb = kmask + b * LL;
    f32x4 Oacc[4] = {{0,0,0,0},{0,0,0,0},{0,0,0,0},{0,0,0,0}};
    float den[4]  = {0.f, 0.f, 0.f, 0.f};
    float*       pw = &Pl[wave][144 * (n >> 3) + 36 * quad + (n & 7)];
    const float* pr = &Pl[wave][9 * lane];
    const int kbeg = wave * (LL / 4);
    const int kend = kbeg + (LL / 4);
    for (int k0 = kbeg; k0 < kend; k0 += 32) {
        const float* krow = Kb + (size_t)k0 * DD;
        bf16x8 kA0 = cvt8(krow);
        bf16x8 kA1 = cvt8(krow + 32);
        bf16x8 kB0 = cvt8(krow + 16 * DD);
        bf16x8 kB1 = cvt8(krow + 16 * DD + 32);
        f32x4 z = {0.f, 0.f, 0.f, 0.f};
        f32x4 S0 = __builtin_amdgcn_mfma_f32_16x16x32_bf16(qf0, kA0, z, 0, 0, 0);
        S0 = __builtin_amdgcn_mfma_f32_16x16x32_bf16(qf1, kA1, S0, 0, 0, 0);
        f32x4 S1 = __builtin_amdgcn_mfma_f32_16x16x32_bf16(qf0, kB0, z, 0, 0, 0);
        S1 = __builtin_amdgcn_mfma_f32_16x16x32_bf16(qf1, kB1, S1, 0, 0, 0);
        float km0 = (float)kmb[k0 + n];
        float km1 = (float)kmb[k0 + 16 + n];
        #pragma unroll
        for (int r = 0; r < 4; ++r) {
            float e0 = __expf(S0[r] * 0.125f) * km0;
            float e1 = __expf(S1[r] * 0.125f) * km1;
            den[r] += e0 + e1;
            pw[9 * r]       = e0;
            pw[288 + 9 * r] = e1;
        }
        __builtin_amdgcn_wave_barrier();
        float pv[8];
        #pragma unroll
        for (int j = 0; j < 8; ++j) pv[j] = pr[j];
        __builtin_amdgcn_wave_barrier();
        union { bf16x8 v; unsigned u[4]; } pf;
        #pragma unroll
        for (int j = 0; j < 4; ++j)
            pf.u[j] = f2bf_u(pv[2 * j]) | (f2bf_u(pv[2 * j + 1]) << 16);
        const float* vrow = Vb + (size_t)k0 * DD;
        #pragma unroll
        for (int db = 0; db < 4; ++db) {
            union { bf16x8 v; unsigned u[4]; } vfr;
            #pragma unroll
            for (int jj = 0; jj < 4; ++jj) {
                unsigned lo  = f2bf_u(vrow[(2 * jj) * DD + db * 16]);
                unsigned hi2 = f2bf_u(vrow[(2 * jj + 1) * DD + db * 16]);
                vfr.u[jj] = lo | (hi2 << 16);
            }
            Oacc[db] = __builtin_amdgcn_mfma_f32_16x16x32_bf16(pf.v, vfr.v, Oacc[db], 0, 0, 0);
        }
    }
    #pragma unroll
    for (int r = 0; r < 4; ++r) {
        float v = den[r];
        v += __shfl_xor(v, 1); v += __shfl_xor(v, 2);
        v += __shfl_xor(v, 4); v += __shfl_xor(v, 8);
        den[r] = v;
    }
    #pragma unroll
    for (int db = 0; db < 4; ++db)
        #pragma unroll
        for (int r = 0; r < 4; ++r)
            Opart[wave][quad * 4 + r][db * 16 + n] = Oacc[db][r];
    if (n == 0) {
        #pragma unroll
        for (int r = 0; r < 4; ++r) Denp[wave][quad * 4 + r] = den[r];
    }
    __syncthreads();
    const int q  = tid >> 4;
    const int d0 = (tid & 15) * 4;
    f32x4 sum = *reinterpret_cast<const f32x4*>(&Opart[0][q][d0]);
    sum += *reinterpret_cast<const f32x4*>(&Opart[1][q][d0]);
    sum += *reinterpret_cast<const f32x4*>(&Opart[2][q][d0]);
    sum += *reinterpret_cast<const f32x4*>(&Opart[3][q][d0]);
    float dn  = Denp[0][q] + Denp[1][q] + Denp[2][q] + Denp[3][q];
    float inv = 1.0f / fmaxf(dn, 1.0f);
    float s   = qmask[b * LL + q0 + q] ? inv : 0.0f;
    f32x4 o   = sum * s;
    float* op = Out + ((size_t)(b * LL + q0 + q)) * DD + d0;
    *reinterpret_cast<f32x4*>(op) = o;
}

extern "C" void kernel_launch(void* const* d_in, const int* in_sizes, int n_in,
                              void* d_out, int out_size, void* d_ws, size_t ws_size,
                              hipStream_t stream) {
    (void)in_sizes; (void)n_in; (void)out_size;
    const float* Q  = (const float*)d_in[0];
    const float* K  = (const float*)d_in[1];
    const float* V  = (const float*)d_in[2];
    const int* qm   = (const int*)d_in[3];
    const int* km   = (const int*)d_in[4];
    float* Out      = (float*)d_out;

    const size_t elems    = (size_t)BB * LL * DD;            // 1,048,576
    const size_t ws_need  = elems * 2 * sizeof(ushort_t);    // 4 MiB
    if (ws_size >= ws_need && d_ws != nullptr) {
        ushort_t* Kbf = (ushort_t*)d_ws;
        ushort_t* VTb = Kbf + elems;
        pack_k_bf16   <<<dim3(elems / (256 * 8)), dim3(256), 0, stream>>>(K, Kbf);
        transpose_v_bf<<<dim3(BB * (LL / 64)),    dim3(256), 0, stream>>>(V, VTb);
        attn6<<<dim3(BB * (LL / 32)), dim3(256), 0, stream>>>(Q, Kbf, VTb, qm, km, Out);
    } else {
        attn_mfma<<<dim3(BB * (LL / 16)), dim3(256), 0, stream>>>(Q, K, V, qm, km, Out);
    }
}

// Round 8
// 117.506 us; speedup vs baseline: 1.0395x; 1.0395x over previous
//
#include <hip/hip_runtime.h>
#include <hip/hip_bf16.h>
#include <stdint.h>

#define BB 8
#define LL 2048
#define DD 64

typedef short bf16x8 __attribute__((ext_vector_type(8)));  // 8 bf16 (4 VGPRs)
typedef float f32x4 __attribute__((ext_vector_type(4)));
typedef unsigned short ushort_t;
typedef __attribute__((address_space(1))) const unsigned int gas_u32;
typedef __attribute__((address_space(3))) unsigned int las_u32;

// ---- helpers --------------------------------------------------------------
__device__ __forceinline__ unsigned pk2(float lo, float hi) {
    union { __hip_bfloat162 h; unsigned u; } c;
    c.h = __float22bfloat162_rn(make_float2(lo, hi));   // v_cvt_pk_bf16_f32
    return c.u;
}
__device__ __forceinline__ float4 ld4(const float* __restrict__ p) {
    return *reinterpret_cast<const float4*>(p);
}
__device__ __forceinline__ bf16x8 cvt8f(float4 a, float4 b) {
    union { bf16x8 v; unsigned u[4]; } r;
    r.u[0] = pk2(a.x, a.y); r.u[1] = pk2(a.z, a.w);
    r.u[2] = pk2(b.x, b.y); r.u[3] = pk2(b.z, b.w);
    return r.v;
}
// async global->LDS, 16B/lane; LDS dst = wave-uniform base + lane*16 (HW rule)
__device__ __forceinline__ void glds16(const void* g, void* lds_base_uniform) {
    __builtin_amdgcn_global_load_lds((gas_u32*)g, (las_u32*)lds_base_uniform, 16, 0, 0);
}
__device__ __forceinline__ float bfu2f(unsigned bits) {
    union { unsigned u; float f; } c; c.u = bits << 16; return c.f;
}
// fallback-kernel helpers (round-2 proven)
__device__ __forceinline__ unsigned f2bf_u(float f) {
    union { float f; unsigned u; } v; v.f = f;
    return (v.u + 0x8000u) >> 16;
}
__device__ __forceinline__ bf16x8 cvt8(const float* __restrict__ p) {
    float4 a = ld4(p), b = ld4(p + 4);
    union { bf16x8 v; unsigned u[4]; } r;
    r.u[0] = f2bf_u(a.x) | (f2bf_u(a.y) << 16);
    r.u[1] = f2bf_u(a.z) | (f2bf_u(a.w) << 16);
    r.u[2] = f2bf_u(b.x) | (f2bf_u(b.y) << 16);
    r.u[3] = f2bf_u(b.z) | (f2bf_u(b.w) << 16);
    return r.v;
}

// ---- prep 1: K fp32 [b][k][d] -> bf16 same layout -------------------------
__global__ __launch_bounds__(256) void pack_k_bf16(const float* __restrict__ K,
                                                   ushort_t* __restrict__ Kb) {
    size_t i = ((size_t)blockIdx.x * 256 + threadIdx.x) * 8;
    float4 a = ld4(K + i), b = ld4(K + i + 4);
    uint4 o = { pk2(a.x, a.y), pk2(a.z, a.w), pk2(b.x, b.y), pk2(b.z, b.w) };
    *reinterpret_cast<uint4*>(Kb + i) = o;
}

// ---- prep 2: V fp32 [b][k][d] -> bf16 transposed [b][d][k] ----------------
__global__ __launch_bounds__(256) void transpose_v_bf(const float* __restrict__ V,
                                                      ushort_t* __restrict__ VT) {
    __shared__ float t[64][65];
    const int b  = blockIdx.x >> 5;
    const int kt = (blockIdx.x & 31) << 6;
    {
        const int r  = threadIdx.x >> 2;
        const int cq = (threadIdx.x & 3) << 4;
        const float* src = V + ((size_t)(b * LL + kt + r)) * DD + cq;
        #pragma unroll
        for (int i = 0; i < 4; ++i) {
            float4 v = ld4(src + 4 * i);
            t[r][cq + 4 * i + 0] = v.x; t[r][cq + 4 * i + 1] = v.y;
            t[r][cq + 4 * i + 2] = v.z; t[r][cq + 4 * i + 3] = v.w;
        }
    }
    __syncthreads();
    {
        const int d  = threadIdx.x >> 2;
        const int kq = (threadIdx.x & 3) << 4;
        ushort_t* dst = VT + ((size_t)(b * DD + d)) * LL + kt + kq;
        #pragma unroll
        for (int u = 0; u < 2; ++u) {
            uint4 o;
            o.x = pk2(t[kq + 8 * u + 0][d], t[kq + 8 * u + 1][d]);
            o.y = pk2(t[kq + 8 * u + 2][d], t[kq + 8 * u + 3][d]);
            o.z = pk2(t[kq + 8 * u + 4][d], t[kq + 8 * u + 5][d]);
            o.w = pk2(t[kq + 8 * u + 6][d], t[kq + 8 * u + 7][d]);
            *reinterpret_cast<uint4*>(dst + 8 * u) = o;
        }
    }
}

// ---- main attention kernel ------------------------------------------------
// Block = 512 thr = 8 waves = (s:0/1 q-subtile) x (h:0..3 k-quarter);
// 32 q/block; k swept in 16 tiles of 128 (staged 32KB/tile, double-buffered
// via global_load_lds w16, XOR-swizzled). Grid = 512 blocks,
// __launch_bounds__(512,4) -> 2 blocks/CU -> 16 waves/CU (4/SIMD): one
// block covers the other's barrier drain; 4 waves/SIMD cover chain latency.
// Per wave per tile: 8 ds_read_b128 + 8 MFMA + one S->exp->shuffle->PV chain.
// Inner math identical to verified R3..R7.
__global__ __launch_bounds__(512, 4) void attn7(
    const float* __restrict__ Q,
    const ushort_t* __restrict__ Kbf,
    const ushort_t* __restrict__ VTb,
    const int* __restrict__ qmask,
    const int* __restrict__ kmask,
    float* __restrict__ Out)
{
    const int tid  = threadIdx.x;
    const int wave = tid >> 6;         // 0..7
    const int lane = tid & 63;
    const int ln   = lane & 15;
    const int quad = lane >> 4;
    const int s    = wave >> 2;        // q-subtile 0..1
    const int h    = wave & 3;         // k-quarter 0..3

    const int b  = blockIdx.x >> 6;          // 8 batches
    const int q0 = (blockIdx.x & 63) << 5;   // 32 q per block

    __shared__ char     lds[2][32768];   // per buf: K 16KB [128k][8 gran] + V 16KB [64d][16 gran]
    __shared__ ushort_t kmbf[LL];        // kmask as bf16 (1.0/0.0)
    __shared__ float    Osum[32][68];
    __shared__ float    Dsum[32];

    // staging geometry: wave w stages K chunks {w, w+8} and V chunks {w, w+8}
    // (chunk = 1KB = 64 granules; lane-linear LDS, XOR-swizzled global source)
    const char* Kg = (const char*)Kbf + (size_t)b * LL * DD * 2;
    const char* Vg = (const char*)VTb + (size_t)b * DD * LL * 2;
    const int krow1 = wave * 8 + (lane >> 3);            // K rows, chunk w
    const int kscol = (lane & 7) ^ (lane >> 3);          // swizzled K src col
    const int vd1   = wave * 4 + (lane >> 4);            // V rows (d), chunk w
    const int vscol = (lane & 15) ^ (vd1 & 15);          // swizzled V src col

    #define STAGE(buf, k0)                                                      \
        do {                                                                    \
            glds16(Kg + (size_t)((k0) + krow1) * 128 + kscol * 16,              \
                   &lds[buf][wave * 1024]);                                     \
            glds16(Kg + (size_t)((k0) + krow1 + 64) * 128 + kscol * 16,         \
                   &lds[buf][(wave + 8) * 1024]);                               \
            glds16(Vg + (size_t)vd1 * (LL * 2) + (k0) * 2 + vscol * 16,         \
                   &lds[buf][16384 + wave * 1024]);                             \
            glds16(Vg + (size_t)(vd1 + 32) * (LL * 2) + (k0) * 2 + vscol * 16,  \
                   &lds[buf][16384 + (wave + 8) * 1024]);                       \
        } while (0)

    STAGE(0, 0);   // tile-0 staging in flight during prologue

    // prologue: zero accum, kmask->bf16, Q fragments
    for (int i = tid; i < 32 * 68; i += 512) (&Osum[0][0])[i] = 0.f;
    if (tid < 32) Dsum[tid] = 0.f;
    {
        int4 a = *reinterpret_cast<const int4*>(kmask + b * LL + tid * 4);
        uint2 u;
        u.x = (a.x ? 0x3F80u : 0u) | ((a.y ? 0x3F80u : 0u) << 16);
        u.y = (a.z ? 0x3F80u : 0u) | ((a.w ? 0x3F80u : 0u) << 16);
        *reinterpret_cast<uint2*>(kmbf + tid * 4) = u;
    }
    bf16x8 qf[2];   // q = q0+16s+ln, d = dh*32+quad*8+j
    {
        const float* qp = Q + ((size_t)(b * LL + q0 + 16 * s + ln)) * DD + quad * 8;
        qf[0] = cvt8f(ld4(qp),      ld4(qp + 4));
        qf[1] = cvt8f(ld4(qp + 32), ld4(qp + 36));
    }

    f32x4 Oacc[4] = {{0,0,0,0},{0,0,0,0},{0,0,0,0},{0,0,0,0}};
    float dsum = 0.f;

    const int src0 = ln + ((quad & 1) << 5);
    const int src1 = src0 + 16;
    const bool hi  = quad >= 2;
    const float EC = 0.125f * 1.44269504f;   // exp(x/8) = exp2(x*EC)

    for (int it = 0; it < 16; ++it) {
        __syncthreads();   // drains staging of tile `it`; other buf now free
        if (it != 15) STAGE((it + 1) & 1, (it + 1) * 128);

        const int   k0 = it * 128;
        const char* LK = lds[it & 1];
        const char* LV = lds[it & 1] + 16384;

        // K A-frags: rows 32h+16tt+ln, d-half dh (swizzled granule col)
        bf16x8 kf[2][2];
        #pragma unroll
        for (int tt = 0; tt < 2; ++tt) {
            const int r = 32 * h + 16 * tt + ln;
            #pragma unroll
            for (int dh = 0; dh < 2; ++dh) {
                const int c = (dh * 4 + quad) ^ (ln & 7);
                kf[tt][dh] = *reinterpret_cast<const bf16x8*>(LK + r * 128 + c * 16);
            }
        }
        // V B-frags: d = db*16+ln, k-local = 32h+8quad+j (swizzled col)
        bf16x8 vf[4];
        #pragma unroll
        for (int db = 0; db < 4; ++db) {
            const int d = db * 16 + ln;
            const int c = (4 * h + quad) ^ ln;
            vf[db] = *reinterpret_cast<const bf16x8*>(LV + d * 256 + c * 16);
        }
        // kmask for this wave's 32k window
        float4 fm[2];
        #pragma unroll
        for (int tt = 0; tt < 2; ++tt) {
            ushort4 mu = *reinterpret_cast<const ushort4*>(
                kmbf + k0 + 32 * h + 16 * tt + 4 * quad);
            fm[tt] = make_float4(bfu2f(mu.x), bfu2f(mu.y), bfu2f(mu.z), bfu2f(mu.w));
        }

        // S^T = K·Q^T; exp2*mask; pack  (lane holds P^T[k=16tt+4quad+r][q=ln])
        unsigned w[2][2];
        #pragma unroll
        for (int tt = 0; tt < 2; ++tt) {
            f32x4 acc = (f32x4){0.f, 0.f, 0.f, 0.f};
            acc = __builtin_amdgcn_mfma_f32_16x16x32_bf16(kf[tt][0], qf[0], acc, 0, 0, 0);
            acc = __builtin_amdgcn_mfma_f32_16x16x32_bf16(kf[tt][1], qf[1], acc, 0, 0, 0);
            float e0 = exp2f(acc[0] * EC) * fm[tt].x;
            float e1 = exp2f(acc[1] * EC) * fm[tt].y;
            float e2 = exp2f(acc[2] * EC) * fm[tt].z;
            float e3 = exp2f(acc[3] * EC) * fm[tt].w;
            dsum += (e0 + e1) + (e2 + e3);
            w[tt][0] = pk2(e0, e1);
            w[tt][1] = pk2(e2, e3);
        }
        // P^T(C-layout) -> P(A-layout): cross-quad permutation (verified)
        union { bf16x8 v; unsigned u[4]; } pf;
        {
            unsigned a0 = __shfl(w[0][0], src0), b0 = __shfl(w[1][0], src0);
            unsigned a1 = __shfl(w[0][1], src0), b1 = __shfl(w[1][1], src0);
            unsigned a2 = __shfl(w[0][0], src1), b2 = __shfl(w[1][0], src1);
            unsigned a3 = __shfl(w[0][1], src1), b3 = __shfl(w[1][1], src1);
            pf.u[0] = hi ? b0 : a0;
            pf.u[1] = hi ? b1 : a1;
            pf.u[2] = hi ? b2 : a2;
            pf.u[3] = hi ? b3 : a3;
        }
        #pragma unroll
        for (int db = 0; db < 4; ++db)
            Oacc[db] = __builtin_amdgcn_mfma_f32_16x16x32_bf16(pf.v, vf[db], Oacc[db], 0, 0, 0);
    }
    #undef STAGE

    // den: reduce over quads (q = ln within subtile s)
    {
        float v = dsum;
        v += __shfl_xor(v, 16);
        v += __shfl_xor(v, 32);
        dsum = v;
    }

    // combine the 8 (s,h) wave partials via LDS atomics (verified epilogue)
    #pragma unroll
    for (int db = 0; db < 4; ++db)
        #pragma unroll
        for (int r = 0; r < 4; ++r)
            atomicAdd(&Osum[16 * s + quad * 4 + r][db * 16 + ln], Oacc[db][r]);
    if (quad == 0) atomicAdd(&Dsum[16 * s + ln], dsum);
    __syncthreads();

    // normalize by max(den,1), apply q_mask, store fp32
    const int q  = tid >> 4;           // 0..31
    const int d0 = (tid & 15) << 2;    // 0..60
    float dn  = Dsum[q];
    float inv = 1.0f / fmaxf(dn, 1.0f);
    float sc  = qmask[b * LL + q0 + q] ? inv : 0.0f;
    f32x4 o = *reinterpret_cast<const f32x4*>(&Osum[q][d0]) * sc;
    float* op = Out + ((size_t)(b * LL + q0 + q)) * DD + d0;
    *reinterpret_cast<f32x4*>(op) = o;
}

// ---- fallback (round-2 kernel, used only if ws too small) -----------------
__global__ __launch_bounds__(256, 4) void attn_mfma(
    const float* __restrict__ Q, const float* __restrict__ K,
    const float* __restrict__ V, const int* __restrict__ qmask,
    const int* __restrict__ kmask, float* __restrict__ Out)
{
    const int tid  = threadIdx.x;
    const int wave = tid >> 6;
    const int lane = tid & 63;
    const int n    = lane & 15;
    const int quad = lane >> 4;
    const int bx = blockIdx.x;
    const int b  = bx >> 7;
    const int q0 = (bx & 127) << 4;
    __shared__ float Pl[4][576];
    __shared__ float Opart[4][16][68];
    __shared__ float Denp[4][16];
    const float* Qp = Q + ((size_t)(b * LL + q0 + n)) * DD + quad * 8;
    bf16x8 qf0 = cvt8(Qp);
    bf16x8 qf1 = cvt8(Qp + 32);
    const float* Kb = K + ((size_t)(b * LL) + n) * DD + quad * 8;
    const float* Vb = V + ((size_t)(b * LL) + quad * 8) * DD + n;
    const int* kmb = kmask + b * LL;
    f32x4 Oacc[4] = {{0,0,0,0},{0,0,0,0},{0,0,0,0},{0,0,0,0}};
    float den[4]  = {0.f, 0.f, 0.f, 0.f};
    float*       pw = &Pl[wave][144 * (n >> 3) + 36 * quad + (n & 7)];
    const float* pr = &Pl[wave][9 * lane];
    const int kbeg = wave * (LL / 4);
    const int kend = kbeg + (LL / 4);
    for (int k0 = kbeg; k0 < kend; k0 += 32) {
        const float* krow = Kb + (size_t)k0 * DD;
        bf16x8 kA0 = cvt8(krow);
        bf16x8 kA1 = cvt8(krow + 32);
        bf16x8 kB0 = cvt8(krow + 16 * DD);
        bf16x8 kB1 = cvt8(krow + 16 * DD + 32);
        f32x4 z = {0.f, 0.f, 0.f, 0.f};
        f32x4 S0 = __builtin_amdgcn_mfma_f32_16x16x32_bf16(qf0, kA0, z, 0, 0, 0);
        S0 = __builtin_amdgcn_mfma_f32_16x16x32_bf16(qf1, kA1, S0, 0, 0, 0);
        f32x4 S1 = __builtin_amdgcn_mfma_f32_16x16x32_bf16(qf0, kB0, z, 0, 0, 0);
        S1 = __builtin_amdgcn_mfma_f32_16x16x32_bf16(qf1, kB1, S1, 0, 0, 0);
        float km0 = (float)kmb[k0 + n];
        float km1 = (float)kmb[k0 + 16 + n];
        #pragma unroll
        for (int r = 0; r < 4; ++r) {
            float e0 = __expf(S0[r] * 0.125f) * km0;
            float e1 = __expf(S1[r] * 0.125f) * km1;
            den[r] += e0 + e1;
            pw[9 * r]       = e0;
            pw[288 + 9 * r] = e1;
        }
        __builtin_amdgcn_wave_barrier();
        float pv[8];
        #pragma unroll
        for (int j = 0; j < 8; ++j) pv[j] = pr[j];
        __builtin_amdgcn_wave_barrier();
        union { bf16x8 v; unsigned u[4]; } pf;
        #pragma unroll
        for (int j = 0; j < 4; ++j)
            pf.u[j] = f2bf_u(pv[2 * j]) | (f2bf_u(pv[2 * j + 1]) << 16);
        const float* vrow = Vb + (size_t)k0 * DD;
        #pragma unroll
        for (int db = 0; db < 4; ++db) {
            union { bf16x8 v; unsigned u[4]; } vfr;
            #pragma unroll
            for (int jj = 0; jj < 4; ++jj) {
                unsigned lo  = f2bf_u(vrow[(2 * jj) * DD + db * 16]);
                unsigned hi2 = f2bf_u(vrow[(2 * jj + 1) * DD + db * 16]);
                vfr.u[jj] = lo | (hi2 << 16);
            }
            Oacc[db] = __builtin_amdgcn_mfma_f32_16x16x32_bf16(pf.v, vfr.v, Oacc[db], 0, 0, 0);
        }
    }
    #pragma unroll
    for (int r = 0; r < 4; ++r) {
        float v = den[r];
        v += __shfl_xor(v, 1); v += __shfl_xor(v, 2);
        v += __shfl_xor(v, 4); v += __shfl_xor(v, 8);
        den[r] = v;
    }
    #pragma unroll
    for (int db = 0; db < 4; ++db)
        #pragma unroll
        for (int r = 0; r < 4; ++r)
            Opart[wave][quad * 4 + r][db * 16 + n] = Oacc[db][r];
    if (n == 0) {
        #pragma unroll
        for (int r = 0; r < 4; ++r) Denp[wave][quad * 4 + r] = den[r];
    }
    __syncthreads();
    const int q  = tid >> 4;
    const int d0 = (tid & 15) * 4;
    f32x4 sum = *reinterpret_cast<const f32x4*>(&Opart[0][q][d0]);
    sum += *reinterpret_cast<const f32x4*>(&Opart[1][q][d0]);
    sum += *reinterpret_cast<const f32x4*>(&Opart[2][q][d0]);
    sum += *reinterpret_cast<const f32x4*>(&Opart[3][q][d0]);
    float dn  = Denp[0][q] + Denp[1][q] + Denp[2][q] + Denp[3][q];
    float inv = 1.0f / fmaxf(dn, 1.0f);
    float s   = qmask[b * LL + q0 + q] ? inv : 0.0f;
    f32x4 o   = sum * s;
    float* op = Out + ((size_t)(b * LL + q0 + q)) * DD + d0;
    *reinterpret_cast<f32x4*>(op) = o;
}

extern "C" void kernel_launch(void* const* d_in, const int* in_sizes, int n_in,
                              void* d_out, int out_size, void* d_ws, size_t ws_size,
                              hipStream_t stream) {
    (void)in_sizes; (void)n_in; (void)out_size;
    const float* Q  = (const float*)d_in[0];
    const float* K  = (const float*)d_in[1];
    const float* V  = (const float*)d_in[2];
    const int* qm   = (const int*)d_in[3];
    const int* km   = (const int*)d_in[4];
    float* Out      = (float*)d_out;

    const size_t elems    = (size_t)BB * LL * DD;            // 1,048,576
    const size_t ws_need  = elems * 2 * sizeof(ushort_t);    // 4 MiB
    if (ws_size >= ws_need && d_ws != nullptr) {
        ushort_t* Kbf = (ushort_t*)d_ws;
        ushort_t* VTb = Kbf + elems;
        pack_k_bf16   <<<dim3(elems / (256 * 8)), dim3(256), 0, stream>>>(K, Kbf);
        transpose_v_bf<<<dim3(BB * (LL / 64)),    dim3(256), 0, stream>>>(V, VTb);
        attn7<<<dim3(BB * (LL / 32)), dim3(512), 0, stream>>>(Q, Kbf, VTb, qm, km, Out);
    } else {
        attn_mfma<<<dim3(BB * (LL / 16)), dim3(256), 0, stream>>>(Q, K, V, qm, km, Out);
    }
}

// Round 9
// 106.188 us; speedup vs baseline: 1.1502x; 1.1066x over previous
//
#include <hip/hip_runtime.h>
#include <hip/hip_bf16.h>
#include <stdint.h>

#define BB 8
#define LL 2048
#define DD 64

typedef short bf16x8 __attribute__((ext_vector_type(8)));  // 8 bf16 (4 VGPRs)
typedef float f32x4 __attribute__((ext_vector_type(4)));
typedef unsigned short ushort_t;
typedef __attribute__((address_space(1))) const unsigned int gas_u32;
typedef __attribute__((address_space(3))) unsigned int las_u32;

// ---- helpers --------------------------------------------------------------
__device__ __forceinline__ unsigned pk2(float lo, float hi) {
    union { __hip_bfloat162 h; unsigned u; } c;
    c.h = __float22bfloat162_rn(make_float2(lo, hi));   // v_cvt_pk_bf16_f32
    return c.u;
}
__device__ __forceinline__ float4 ld4(const float* __restrict__ p) {
    return *reinterpret_cast<const float4*>(p);
}
__device__ __forceinline__ bf16x8 cvt8f(float4 a, float4 b) {
    union { bf16x8 v; unsigned u[4]; } r;
    r.u[0] = pk2(a.x, a.y); r.u[1] = pk2(a.z, a.w);
    r.u[2] = pk2(b.x, b.y); r.u[3] = pk2(b.z, b.w);
    return r.v;
}
// async global->LDS, 16B/lane; LDS dst = wave-uniform base + lane*16 (HW rule)
__device__ __forceinline__ void glds16(const void* g, void* lds_base_uniform) {
    __builtin_amdgcn_global_load_lds((gas_u32*)g, (las_u32*)lds_base_uniform, 16, 0, 0);
}
__device__ __forceinline__ float bfu2f(unsigned bits) {
    union { unsigned u; float f; } c; c.u = bits << 16; return c.f;
}
// fallback-kernel helpers (round-2 proven)
__device__ __forceinline__ unsigned f2bf_u(float f) {
    union { float f; unsigned u; } v; v.f = f;
    return (v.u + 0x8000u) >> 16;
}
__device__ __forceinline__ bf16x8 cvt8(const float* __restrict__ p) {
    float4 a = ld4(p), b = ld4(p + 4);
    union { bf16x8 v; unsigned u[4]; } r;
    r.u[0] = f2bf_u(a.x) | (f2bf_u(a.y) << 16);
    r.u[1] = f2bf_u(a.z) | (f2bf_u(a.w) << 16);
    r.u[2] = f2bf_u(b.x) | (f2bf_u(b.y) << 16);
    r.u[3] = f2bf_u(b.z) | (f2bf_u(b.w) << 16);
    return r.v;
}

// ---- prep 1: K fp32 [b][k][d] -> bf16 same layout -------------------------
__global__ __launch_bounds__(256) void pack_k_bf16(const float* __restrict__ K,
                                                   ushort_t* __restrict__ Kb) {
    size_t i = ((size_t)blockIdx.x * 256 + threadIdx.x) * 8;
    float4 a = ld4(K + i), b = ld4(K + i + 4);
    uint4 o = { pk2(a.x, a.y), pk2(a.z, a.w), pk2(b.x, b.y), pk2(b.z, b.w) };
    *reinterpret_cast<uint4*>(Kb + i) = o;
}

// ---- prep 2: V fp32 [b][k][d] -> bf16 transposed [b][d][k] ----------------
__global__ __launch_bounds__(256) void transpose_v_bf(const float* __restrict__ V,
                                                      ushort_t* __restrict__ VT) {
    __shared__ float t[64][65];
    const int b  = blockIdx.x >> 5;
    const int kt = (blockIdx.x & 31) << 6;
    {
        const int r  = threadIdx.x >> 2;
        const int cq = (threadIdx.x & 3) << 4;
        const float* src = V + ((size_t)(b * LL + kt + r)) * DD + cq;
        #pragma unroll
        for (int i = 0; i < 4; ++i) {
            float4 v = ld4(src + 4 * i);
            t[r][cq + 4 * i + 0] = v.x; t[r][cq + 4 * i + 1] = v.y;
            t[r][cq + 4 * i + 2] = v.z; t[r][cq + 4 * i + 3] = v.w;
        }
    }
    __syncthreads();
    {
        const int d  = threadIdx.x >> 2;
        const int kq = (threadIdx.x & 3) << 4;
        ushort_t* dst = VT + ((size_t)(b * DD + d)) * LL + kt + kq;
        #pragma unroll
        for (int u = 0; u < 2; ++u) {
            uint4 o;
            o.x = pk2(t[kq + 8 * u + 0][d], t[kq + 8 * u + 1][d]);
            o.y = pk2(t[kq + 8 * u + 2][d], t[kq + 8 * u + 3][d]);
            o.z = pk2(t[kq + 8 * u + 4][d], t[kq + 8 * u + 5][d]);
            o.w = pk2(t[kq + 8 * u + 6][d], t[kq + 8 * u + 7][d]);
            *reinterpret_cast<uint4*>(dst + 8 * u) = o;
        }
    }
}

// ---- main attention kernel ------------------------------------------------
// 128-q tile + 4-way grid split-k: staged volume drops 256 MB -> 64 MB
// (the measured ~5 TB/s global_load_lds ingest was the R5-R8 wall).
// Block = 512 thr = 8 waves; wave w owns q-subtile w (16 q) over the block's
// FULL 512-k range -> no intra-block combine. 8 tiles of 64 k, 16 KB/tile
// staged double-buffered (LDS 33 KB -> 2 blocks/CU). Per wave per tile:
// 16 ds_read_b128 + 16 MFMA + verified S->exp->shuffle->PV chain (x2 32-k
// groups). Partials (O 128x64 + den 128) to d_ws; reduce kernel normalizes.
// blockIdx: ksp = bx&3, qt = (bx>>2)&15, b = bx>>6.
__global__ __launch_bounds__(512, 4) void attn8(
    const float* __restrict__ Q,
    const ushort_t* __restrict__ Kbf,
    const ushort_t* __restrict__ VTb,
    const int* __restrict__ kmask,
    float* __restrict__ Opart)
{
    const int tid  = threadIdx.x;
    const int wave = tid >> 6;         // q-subtile 0..7
    const int lane = tid & 63;
    const int ln   = lane & 15;
    const int quad = lane >> 4;

    const int bx    = blockIdx.x;
    const int ksp   = bx & 3;
    const int qt    = (bx >> 2) & 15;
    const int b     = bx >> 6;
    const int q0    = qt * 128;
    const int kbase = ksp * 512;

    __shared__ char     lds[2][16384];   // per buf: K 8KB [64k][128B] + V 8KB [64d][128B]
    __shared__ ushort_t kmbf[512];       // kmask (block's k-range) as bf16

    // staging geometry: lane g=tid stages 1 K granule + 1 V granule per tile
    const char* Kg = (const char*)Kbf + (size_t)b * LL * DD * 2;
    const char* Vg = (const char*)VTb + (size_t)b * DD * LL * 2;
    const int gr = tid >> 3;                  // row 0..63 (k for K, d for V)
    const int gc = (tid & 7) ^ (gr & 7);      // swizzled source granule col

    #define STAGE(buf, k0)                                                     \
        do {                                                                   \
            glds16(Kg + (size_t)(kbase + (k0) + gr) * 128 + gc * 16,           \
                   &lds[buf][wave * 1024]);                                    \
            glds16(Vg + (size_t)gr * (LL * 2) + (kbase + (k0)) * 2 + gc * 16,  \
                   &lds[buf][8192 + wave * 1024]);                             \
        } while (0)

    STAGE(0, 0);   // tile-0 staging in flight during prologue

    // prologue: kmask->bf16 (block k-range), Q fragments
    if (tid < 128) {
        int4 a = *reinterpret_cast<const int4*>(kmask + b * LL + kbase + tid * 4);
        uint2 u;
        u.x = (a.x ? 0x3F80u : 0u) | ((a.y ? 0x3F80u : 0u) << 16);
        u.y = (a.z ? 0x3F80u : 0u) | ((a.w ? 0x3F80u : 0u) << 16);
        *reinterpret_cast<uint2*>(kmbf + tid * 4) = u;
    }
    bf16x8 qf[2];   // q = q0+16*wave+ln, d = dh*32+quad*8+j
    {
        const float* qp = Q + ((size_t)(b * LL + q0 + 16 * wave + ln)) * DD + quad * 8;
        qf[0] = cvt8f(ld4(qp),      ld4(qp + 4));
        qf[1] = cvt8f(ld4(qp + 32), ld4(qp + 36));
    }

    f32x4 Oacc[4] = {{0,0,0,0},{0,0,0,0},{0,0,0,0},{0,0,0,0}};
    float dsum = 0.f;

    const int src0 = ln + ((quad & 1) << 5);
    const int src1 = src0 + 16;
    const bool hi  = quad >= 2;
    const float EC = 0.125f * 1.44269504f;   // exp(x/8) = exp2(x*EC)

    for (int it = 0; it < 8; ++it) {
        __syncthreads();   // drains staging of tile `it`; other buf now free
        if (it != 7) STAGE((it + 1) & 1, (it + 1) * 64);

        const char* LK = lds[it & 1];
        const char* LV = lds[it & 1] + 8192;

        // K A-frags: rows 16tt+ln, d-half dh (swizzled granule col)
        bf16x8 kf[4][2];
        #pragma unroll
        for (int tt = 0; tt < 4; ++tt) {
            const int r = 16 * tt + ln;
            #pragma unroll
            for (int dh = 0; dh < 2; ++dh) {
                const int c = (dh * 4 + quad) ^ (ln & 7);
                kf[tt][dh] = *reinterpret_cast<const bf16x8*>(LK + r * 128 + c * 16);
            }
        }
        // V B-frags: d = db*16+ln, k-local = 32*kh + 8*quad + j (swizzled col)
        bf16x8 vf[2][4];
        #pragma unroll
        for (int kh = 0; kh < 2; ++kh) {
            const int c = (kh * 4 + quad) ^ (ln & 7);
            #pragma unroll
            for (int db = 0; db < 4; ++db) {
                const int d = db * 16 + ln;
                vf[kh][db] = *reinterpret_cast<const bf16x8*>(LV + d * 128 + c * 16);
            }
        }

        // S^T = K·Q^T; exp2*mask; pack  (lane holds P^T[k=16tt+4quad+r][q=ln])
        unsigned w[4][2];
        #pragma unroll
        for (int tt = 0; tt < 4; ++tt) {
            f32x4 acc = (f32x4){0.f, 0.f, 0.f, 0.f};
            acc = __builtin_amdgcn_mfma_f32_16x16x32_bf16(kf[tt][0], qf[0], acc, 0, 0, 0);
            acc = __builtin_amdgcn_mfma_f32_16x16x32_bf16(kf[tt][1], qf[1], acc, 0, 0, 0);
            ushort4 mu = *reinterpret_cast<const ushort4*>(
                kmbf + it * 64 + 16 * tt + 4 * quad);
            float e0 = exp2f(acc[0] * EC) * bfu2f(mu.x);
            float e1 = exp2f(acc[1] * EC) * bfu2f(mu.y);
            float e2 = exp2f(acc[2] * EC) * bfu2f(mu.z);
            float e3 = exp2f(acc[3] * EC) * bfu2f(mu.w);
            dsum += (e0 + e1) + (e2 + e3);
            w[tt][0] = pk2(e0, e1);
            w[tt][1] = pk2(e2, e3);
        }
        // P^T(C-layout) -> P(A-layout) per 32-k group, then PV (verified)
        #pragma unroll
        for (int g = 0; g < 2; ++g) {
            union { bf16x8 v; unsigned u[4]; } pf;
            unsigned a0 = __shfl(w[2*g][0], src0), b0 = __shfl(w[2*g+1][0], src0);
            unsigned a1 = __shfl(w[2*g][1], src0), b1 = __shfl(w[2*g+1][1], src0);
            unsigned a2 = __shfl(w[2*g][0], src1), b2 = __shfl(w[2*g+1][0], src1);
            unsigned a3 = __shfl(w[2*g][1], src1), b3 = __shfl(w[2*g+1][1], src1);
            pf.u[0] = hi ? b0 : a0;
            pf.u[1] = hi ? b1 : a1;
            pf.u[2] = hi ? b2 : a2;
            pf.u[3] = hi ? b3 : a3;
            #pragma unroll
            for (int db = 0; db < 4; ++db)
                Oacc[db] = __builtin_amdgcn_mfma_f32_16x16x32_bf16(pf.v, vf[g][db], Oacc[db], 0, 0, 0);
        }
    }
    #undef STAGE

    // den: reduce over quads (q = 16*wave + ln)
    {
        float v = dsum;
        v += __shfl_xor(v, 16);
        v += __shfl_xor(v, 32);
        dsum = v;
    }

    // write block partial: O rows q_local = 16*wave + quad*4 + r, col db*16+ln
    float* pb = Opart + (size_t)bx * 8320;   // 128*64 O + 128 den
    #pragma unroll
    for (int db = 0; db < 4; ++db)
        #pragma unroll
        for (int r = 0; r < 4; ++r)
            pb[(16 * wave + quad * 4 + r) * 64 + db * 16 + ln] = Oacc[db][r];
    if (quad == 0) pb[8192 + 16 * wave + ln] = dsum;
}

// ---- reduce: sum 4 k-split partials, normalize, mask, write Out -----------
__global__ __launch_bounds__(256) void reduce_norm(
    const float* __restrict__ Opart,
    const int* __restrict__ qmask,
    float* __restrict__ Out)
{
    const int rb = blockIdx.x;         // 8b x 16qt = 128
    const int qt = rb & 15;
    const int b  = rb >> 4;
    const int t  = threadIdx.x;
    const int q  = t >> 1;             // 0..127
    const int d0 = (t & 1) * 32;

    const float* p0 = Opart + (size_t)((b * 16 + qt) * 4 + 0) * 8320;
    const float* p1 = p0 + 8320;
    const float* p2 = p1 + 8320;
    const float* p3 = p2 + 8320;

    float dn = p0[8192 + q] + p1[8192 + q] + p2[8192 + q] + p3[8192 + q];
    float sc = qmask[b * LL + qt * 128 + q] ? (1.0f / fmaxf(dn, 1.0f)) : 0.0f;

    const int off = q * 64 + d0;
    float* op = Out + ((size_t)(b * LL + qt * 128 + q)) * DD + d0;
    #pragma unroll
    for (int i = 0; i < 8; ++i) {
        f32x4 v = *reinterpret_cast<const f32x4*>(p0 + off + 4 * i)
                + *reinterpret_cast<const f32x4*>(p1 + off + 4 * i)
                + *reinterpret_cast<const f32x4*>(p2 + off + 4 * i)
                + *reinterpret_cast<const f32x4*>(p3 + off + 4 * i);
        *reinterpret_cast<f32x4*>(op + 4 * i) = v * sc;
    }
}

// ---- fallback (round-2 kernel, used only if ws too small) -----------------
__global__ __launch_bounds__(256, 4) void attn_mfma(
    const float* __restrict__ Q, const float* __restrict__ K,
    const float* __restrict__ V, const int* __restrict__ qmask,
    const int* __restrict__ kmask, float* __restrict__ Out)
{
    const int tid  = threadIdx.x;
    const int wave = tid >> 6;
    const int lane = tid & 63;
    const int n    = lane & 15;
    const int quad = lane >> 4;
    const int bx = blockIdx.x;
    const int b  = bx >> 7;
    const int q0 = (bx & 127) << 4;
    __shared__ float Pl[4][576];
    __shared__ float Opart2[4][16][68];
    __shared__ float Denp[4][16];
    const float* Qp = Q + ((size_t)(b * LL + q0 + n)) * DD + quad * 8;
    bf16x8 qf0 = cvt8(Qp);
    bf16x8 qf1 = cvt8(Qp + 32);
    const float* Kb = K + ((size_t)(b * LL) + n) * DD + quad * 8;
    const float* Vb = V + ((size_t)(b * LL) + quad * 8) * DD + n;
    const int* kmb = kmask + b * LL;
    f32x4 Oacc[4] = {{0,0,0,0},{0,0,0,0},{0,0,0,0},{0,0,0,0}};
    float den[4]  = {0.f, 0.f, 0.f, 0.f};
    float*       pw = &Pl[wave][144 * (n >> 3) + 36 * quad + (n & 7)];
    const float* pr = &Pl[wave][9 * lane];
    const int kbeg = wave * (LL / 4);
    const int kend = kbeg + (LL / 4);
    for (int k0 = kbeg; k0 < kend; k0 += 32) {
        const float* krow = Kb + (size_t)k0 * DD;
        bf16x8 kA0 = cvt8(krow);
        bf16x8 kA1 = cvt8(krow + 32);
        bf16x8 kB0 = cvt8(krow + 16 * DD);
        bf16x8 kB1 = cvt8(krow + 16 * DD + 32);
        f32x4 z = {0.f, 0.f, 0.f, 0.f};
        f32x4 S0 = __builtin_amdgcn_mfma_f32_16x16x32_bf16(qf0, kA0, z, 0, 0, 0);
        S0 = __builtin_amdgcn_mfma_f32_16x16x32_bf16(qf1, kA1, S0, 0, 0, 0);
        f32x4 S1 = __builtin_amdgcn_mfma_f32_16x16x32_bf16(qf0, kB0, z, 0, 0, 0);
        S1 = __builtin_amdgcn_mfma_f32_16x16x32_bf16(qf1, kB1, S1, 0, 0, 0);
        float km0 = (float)kmb[k0 + n];
        float km1 = (float)kmb[k0 + 16 + n];
        #pragma unroll
        for (int r = 0; r < 4; ++r) {
            float e0 = __expf(S0[r] * 0.125f) * km0;
            float e1 = __expf(S1[r] * 0.125f) * km1;
            den[r] += e0 + e1;
            pw[9 * r]       = e0;
            pw[288 + 9 * r] = e1;
        }
        __builtin_amdgcn_wave_barrier();
        float pv[8];
        #pragma unroll
        for (int j = 0; j < 8; ++j) pv[j] = pr[j];
        __builtin_amdgcn_wave_barrier();
        union { bf16x8 v; unsigned u[4]; } pf;
        #pragma unroll
        for (int j = 0; j < 4; ++j)
            pf.u[j] = f2bf_u(pv[2 * j]) | (f2bf_u(pv[2 * j + 1]) << 16);
        const float* vrow = Vb + (size_t)k0 * DD;
        #pragma unroll
        for (int db = 0; db < 4; ++db) {
            union { bf16x8 v; unsigned u[4]; } vfr;
            #pragma unroll
            for (int jj = 0; jj < 4; ++jj) {
                unsigned lo  = f2bf_u(vrow[(2 * jj) * DD + db * 16]);
                unsigned hi2 = f2bf_u(vrow[(2 * jj + 1) * DD + db * 16]);
                vfr.u[jj] = lo | (hi2 << 16);
            }
            Oacc[db] = __builtin_amdgcn_mfma_f32_16x16x32_bf16(pf.v, vfr.v, Oacc[db], 0, 0, 0);
        }
    }
    #pragma unroll
    for (int r = 0; r < 4; ++r) {
        float v = den[r];
        v += __shfl_xor(v, 1); v += __shfl_xor(v, 2);
        v += __shfl_xor(v, 4); v += __shfl_xor(v, 8);
        den[r] = v;
    }
    #pragma unroll
    for (int db = 0; db < 4; ++db)
        #pragma unroll
        for (int r = 0; r < 4; ++r)
            Opart2[wave][quad * 4 + r][db * 16 + n] = Oacc[db][r];
    if (n == 0) {
        #pragma unroll
        for (int r = 0; r < 4; ++r) Denp[wave][quad * 4 + r] = den[r];
    }
    __syncthreads();
    const int q  = tid >> 4;
    const int d0 = (tid & 15) * 4;
    f32x4 sum = *reinterpret_cast<const f32x4*>(&Opart2[0][q][d0]);
    sum += *reinterpret_cast<const f32x4*>(&Opart2[1][q][d0]);
    sum += *reinterpret_cast<const f32x4*>(&Opart2[2][q][d0]);
    sum += *reinterpret_cast<const f32x4*>(&Opart2[3][q][d0]);
    float dn  = Denp[0][q] + Denp[1][q] + Denp[2][q] + Denp[3][q];
    float inv = 1.0f / fmaxf(dn, 1.0f);
    float s   = qmask[b * LL + q0 + q] ? inv : 0.0f;
    f32x4 o   = sum * s;
    float* op = Out + ((size_t)(b * LL + q0 + q)) * DD + d0;
    *reinterpret_cast<f32x4*>(op) = o;
}

extern "C" void kernel_launch(void* const* d_in, const int* in_sizes, int n_in,
                              void* d_out, int out_size, void* d_ws, size_t ws_size,
                              hipStream_t stream) {
    (void)in_sizes; (void)n_in; (void)out_size;
    const float* Q  = (const float*)d_in[0];
    const float* K  = (const float*)d_in[1];
    const float* V  = (const float*)d_in[2];
    const int* qm   = (const int*)d_in[3];
    const int* km   = (const int*)d_in[4];
    float* Out      = (float*)d_out;

    const size_t elems   = (size_t)BB * LL * DD;             // 1,048,576
    const size_t part_off = 4u * 1024 * 1024;                // after Kbf+VTb
    const size_t ws_need  = part_off + (size_t)512 * 8320 * sizeof(float); // ~21.3 MB
    if (ws_size >= ws_need && d_ws != nullptr) {
        ushort_t* Kbf = (ushort_t*)d_ws;
        ushort_t* VTb = Kbf + elems;
        float* Opart  = (float*)((char*)d_ws + part_off);
        pack_k_bf16   <<<dim3(elems / (256 * 8)), dim3(256), 0, stream>>>(K, Kbf);
        transpose_v_bf<<<dim3(BB * (LL / 64)),    dim3(256), 0, stream>>>(V, VTb);
        attn8<<<dim3(512), dim3(512), 0, stream>>>(Q, Kbf, VTb, km, Opart);
        reduce_norm<<<dim3(128), dim3(256), 0, stream>>>(Opart, qm, Out);
    } else {
        attn_mfma<<<dim3(BB * (LL / 16)), dim3(256), 0, stream>>>(Q, K, V, qm, km, Out);
    }
}